// Round 8
// baseline (144.731 us; speedup 1.0000x reference)
//
#include <hip/hip_runtime.h>
#include <hip/hip_cooperative_groups.h>
#include <math.h>

namespace cg = cooperative_groups;

#define GAMMA 0.999f
#define LAM   0.95f
#define GL    (GAMMA * LAM)

constexpr int T    = 4096;
constexpr int NENV = 1024;

// Segment summary: adv entering from later time is x.
//   transfer: adv_out = P + Q*x
//   sum adv^2    = s2 + 2*spq*x + sq2*x^2
//   sum logp*adv = slpp + slpq*x
struct Seg { float P, Q, s2, spq, sq2, slpp, slpq; };

// A = earlier-time (outer), B = later-time (inner, applied first).
__device__ __forceinline__ Seg seg_combine(const Seg& A, const Seg& B) {
    Seg r;
    const float qb = B.Q, pb = B.P;
    r.s2   = B.s2 + A.s2 + 2.f * A.spq * pb + A.sq2 * pb * pb;
    r.spq  = B.spq + (A.spq + A.sq2 * pb) * qb;
    r.sq2  = B.sq2 + A.sq2 * qb * qb;
    r.slpp = B.slpp + A.slpp + A.slpq * pb;
    r.slpq = B.slpq + A.slpq * qb;
    r.P    = A.P + A.Q * pb;
    r.Q    = A.Q * qb;
    return r;
}

// Single cooperative kernel: phase1 chunk scans -> grid sync -> phase2 per-env
// monoid tree-reduce -> grid sync -> phase3 scalar assembly.
// Grid = 2*C blocks x 256 thr; 2 blocks/CU (co-resident for cooperative sync).
__global__ __launch_bounds__(256, 2) void gae_fused(
    const float* __restrict__ R, const float* __restrict__ LP,
    const float* __restrict__ V, const float* __restrict__ LV,
    const float* __restrict__ E, const float* __restrict__ M,
    float* __restrict__ summ, float* __restrict__ entp,
    float* __restrict__ part, float* __restrict__ out, int C, int L)
{
    cg::grid_group grid = cg::this_grid();
    const int b    = blockIdx.x;
    const int tid  = threadIdx.x;
    const int lane = tid & 63;
    const int w    = tid >> 6;
    __shared__ float ls[4];

    // ---------------- Phase 1: per (chunk, env-pair) backward scan ----------
    {
        const int c    = b >> 1;
        const int env  = 2 * ((b & 1) * 256 + tid);   // even env index
        const int t_lo = c * L;
        const int t_hi = t_lo + L - 1;

        float2 vn = (c == C - 1) ? *(const float2*)(LV + env)
                                 : *(const float2*)(V + (size_t)(t_hi + 1) * NENV + env);

        float p0=0.f,q0=1.f,s20=0.f,spq0=0.f,sq20=0.f,slpp0=0.f,slpq0=0.f;
        float p1=0.f,q1=1.f,s21=0.f,spq1=0.f,sq21=0.f,slpp1=0.f,slpq1=0.f;
        float sent = 0.f;

        #pragma unroll 4
        for (int t = t_hi; t >= t_lo; --t) {
            const size_t idx = (size_t)t * NENV + env;
            const float2 r  = *(const float2*)(R  + idx);
            const float2 v  = *(const float2*)(V  + idx);
            const float2 m  = *(const float2*)(M  + idx);
            const float2 lp = *(const float2*)(LP + idx);
            const float2 e  = *(const float2*)(E  + idx);

            float ret = fmaf(GAMMA * vn.x, m.x, r.x);
            float a   = ret - v.x;
            float bb  = GL * m.x;
            p0 = fmaf(bb, p0, a); q0 = bb * q0;
            s20 = fmaf(p0, p0, s20); spq0 = fmaf(p0, q0, spq0); sq20 = fmaf(q0, q0, sq20);
            slpp0 = fmaf(lp.x, p0, slpp0); slpq0 = fmaf(lp.x, q0, slpq0);

            ret = fmaf(GAMMA * vn.y, m.y, r.y);
            a   = ret - v.y;
            bb  = GL * m.y;
            p1 = fmaf(bb, p1, a); q1 = bb * q1;
            s21 = fmaf(p1, p1, s21); spq1 = fmaf(p1, q1, spq1); sq21 = fmaf(q1, q1, sq21);
            slpp1 = fmaf(lp.y, p1, slpp1); slpq1 = fmaf(lp.y, q1, slpq1);

            sent += e.x + e.y;
            vn = v;
        }

        float4* s0 = (float4*)(summ + ((size_t)env * C + c) * 8);
        s0[0] = make_float4(p0, q0, s20, spq0);
        s0[1] = make_float4(sq20, slpp0, slpq0, 0.f);
        float4* s1 = (float4*)(summ + ((size_t)(env + 1) * C + c) * 8);
        s1[0] = make_float4(p1, q1, s21, spq1);
        s1[1] = make_float4(sq21, slpp1, slpq1, 0.f);

        #pragma unroll
        for (int o = 32; o > 0; o >>= 1) sent += __shfl_down(sent, o, 64);
        if (lane == 0) ls[w] = sent;
        __syncthreads();
        if (tid == 0) entp[b] = (ls[0] + ls[1]) + (ls[2] + ls[3]);
    }

    grid.sync();

    // ---------------- Phase 2: per-env ordered tree-reduce (blocks 0..255) --
    if (b < 256) {
        const int env  = b * 4 + w;
        const int K    = C >> 6;
        const int c_hi = C - 1 - lane * K;

        const float* base = summ + ((size_t)env * C + c_hi) * 8;
        float4 a0 = ((const float4*)base)[0];
        float4 a1 = ((const float4*)base)[1];
        Seg cur = { a0.x, a0.y, a0.z, a0.w, a1.x, a1.y, a1.z };

        for (int j = 1; j < K; ++j) {
            const float* bp = summ + ((size_t)env * C + (c_hi - j)) * 8;
            float4 b0 = ((const float4*)bp)[0];
            float4 b1 = ((const float4*)bp)[1];
            Seg A = { b0.x, b0.y, b0.z, b0.w, b1.x, b1.y, b1.z };
            cur = seg_combine(A, cur);   // A is earlier time
        }

        #pragma unroll
        for (int d = 1; d < 64; d <<= 1) {
            Seg o;
            o.P    = __shfl_down(cur.P,    d, 64);
            o.Q    = __shfl_down(cur.Q,    d, 64);
            o.s2   = __shfl_down(cur.s2,   d, 64);
            o.spq  = __shfl_down(cur.spq,  d, 64);
            o.sq2  = __shfl_down(cur.sq2,  d, 64);
            o.slpp = __shfl_down(cur.slpp, d, 64);
            o.slpq = __shfl_down(cur.slpq, d, 64);
            cur = seg_combine(o, cur);   // higher lane = earlier time = outer
        }

        if (lane == 0) {   // x = 0 at the latest timestep
            part[env * 2 + 0] = cur.s2;
            part[env * 2 + 1] = cur.slpp;
        }
    }

    grid.sync();

    // ---------------- Phase 3: final scalar reduction (block 0) -------------
    if (b == 0) {
        const int nent = 2 * C;
        float crit = 0.f, act = 0.f, ent = 0.f;
        for (int i = tid; i < NENV; i += 256) {
            crit += part[2 * i + 0];
            act  += part[2 * i + 1];
        }
        for (int i = tid; i < nent; i += 256) ent += entp[i];

        #pragma unroll
        for (int o = 32; o > 0; o >>= 1) {
            crit += __shfl_down(crit, o, 64);
            act  += __shfl_down(act,  o, 64);
            ent  += __shfl_down(ent,  o, 64);
        }
        __shared__ float lc[4], la[4], le[4];
        if (lane == 0) { lc[w] = crit; la[w] = act; le[w] = ent; }
        __syncthreads();
        if (tid == 0) {
            crit = (lc[0] + lc[1]) + (lc[2] + lc[3]);
            act  = (la[0] + la[1]) + (la[2] + la[3]);
            ent  = (le[0] + le[1]) + (le[2] + le[3]);
            const float inv = 1.f / (float)((size_t)T * NENV);
            out[0] = crit * inv;
            out[1] = -act * inv - 0.01f * (ent * inv);
        }
    }
}

extern "C" void kernel_launch(void* const* d_in, const int* in_sizes, int n_in,
                              void* d_out, int out_size, void* d_ws, size_t ws_size,
                              hipStream_t stream) {
    const float* R  = (const float*)d_in[0];
    const float* LP = (const float*)d_in[1];
    const float* V  = (const float*)d_in[2];
    const float* LV = (const float*)d_in[3];
    const float* E  = (const float*)d_in[4];
    const float* M  = (const float*)d_in[5];
    float* out = (float*)d_out;

    // C chunks (power of two, >=128 so phase2's 256-block mapping holds).
    int C = 256;
    {
        size_t need = ((size_t)C * 8 * NENV + (size_t)C * 2 + 2 * NENV) * sizeof(float);
        if (need > ws_size) C = 128;
    }
    const int L = T / C;

    float* summ = (float*)d_ws;                      // C*8*NENV
    float* entp = summ + (size_t)C * 8 * NENV;       // 2*C
    float* part = entp + (size_t)C * 2;              // 2*NENV

    void* args[] = { (void*)&R, (void*)&LP, (void*)&V, (void*)&LV, (void*)&E,
                     (void*)&M, (void*)&summ, (void*)&entp, (void*)&part,
                     (void*)&out, (void*)&C, (void*)&L };
    hipLaunchCooperativeKernel((const void*)gae_fused, dim3(C * 2), dim3(256),
                               args, 0, stream);
}

// Round 10
// 34.493 us; speedup vs baseline: 4.1959x; 4.1959x over previous
//
#include <hip/hip_runtime.h>
#include <math.h>

#define GAMMA 0.999f
#define LAM   0.95f
#define GL    (GAMMA * LAM)

constexpr int T    = 4096;
constexpr int NENV = 1024;
constexpr int C    = 256;         // chunks
constexpr int L    = T / C;       // 16 timesteps per chunk

// Segment summary: adv entering from later time is x.
//   transfer: adv_out = P + Q*x
//   sum adv^2    = s2 + 2*spq*x + sq2*x^2
//   sum logp*adv = slpp + slpq*x
struct Seg { float P, Q, s2, spq, sq2, slpp, slpq; };

// A = earlier-time (outer), B = later-time (inner, applied first).
__device__ __forceinline__ Seg seg_combine(const Seg& A, const Seg& B) {
    Seg r;
    const float qb = B.Q, pb = B.P;
    r.s2   = B.s2 + A.s2 + 2.f * A.spq * pb + A.sq2 * pb * pb;
    r.spq  = B.spq + (A.spq + A.sq2 * pb) * qb;
    r.sq2  = B.sq2 + A.sq2 * qb * qb;
    r.slpp = B.slpp + A.slpp + A.slpq * pb;
    r.slpq = B.slpq + A.slpq * qb;
    r.P    = A.P + A.Q * pb;
    r.Q    = A.Q * qb;
    return r;
}

// Pass 1: per-chunk backward scan, 4 envs/thread (float4 loads, 16B/lane).
// Grid = C blocks x 256 thr. Also resets the pass2 completion counter.
__global__ __launch_bounds__(256) void gae_pass1(
    const float* __restrict__ R, const float* __restrict__ LP,
    const float* __restrict__ V, const float* __restrict__ LV,
    const float* __restrict__ E, const float* __restrict__ M,
    float* __restrict__ summ, float* __restrict__ entp,
    unsigned int* __restrict__ cnt)
{
    if (blockIdx.x == 0 && threadIdx.x == 0) *cnt = 0u;  // stream-ordered reset

    const int c    = blockIdx.x;
    const int e0   = threadIdx.x * 4;
    const int t_lo = c * L;
    const int t_hi = t_lo + L - 1;

    float4 vn = (c == C - 1) ? *(const float4*)(LV + e0)
                             : *(const float4*)(V + (size_t)(t_hi + 1) * NENV + e0);

    float p[4], q[4], s2[4], spq[4], sq2[4], slpp[4], slpq[4];
    #pragma unroll
    for (int j = 0; j < 4; ++j) {
        p[j] = 0.f; q[j] = 1.f; s2[j] = 0.f; spq[j] = 0.f; sq2[j] = 0.f;
        slpp[j] = 0.f; slpq[j] = 0.f;
    }
    float sent = 0.f;

    #pragma unroll 4
    for (int t = t_hi; t >= t_lo; --t) {
        const size_t idx = (size_t)t * NENV + e0;
        const float4 r4  = *(const float4*)(R  + idx);
        const float4 v4  = *(const float4*)(V  + idx);
        const float4 m4  = *(const float4*)(M  + idx);
        const float4 lp4 = *(const float4*)(LP + idx);
        const float4 e4  = *(const float4*)(E  + idx);

        const float* rr = (const float*)&r4;
        const float* vv = (const float*)&v4;
        const float* mm = (const float*)&m4;
        const float* ll = (const float*)&lp4;
        const float* ee = (const float*)&e4;
        float* vnf = (float*)&vn;

        #pragma unroll
        for (int j = 0; j < 4; ++j) {
            const float ret = fmaf(GAMMA * vnf[j], mm[j], rr[j]);
            const float a   = ret - vv[j];
            const float b   = GL * mm[j];
            p[j] = fmaf(b, p[j], a);
            q[j] = b * q[j];
            s2[j]   = fmaf(p[j], p[j], s2[j]);
            spq[j]  = fmaf(p[j], q[j], spq[j]);
            sq2[j]  = fmaf(q[j], q[j], sq2[j]);
            slpp[j] = fmaf(ll[j], p[j], slpp[j]);
            slpq[j] = fmaf(ll[j], q[j], slpq[j]);
            sent += ee[j];
        }
        vn = v4;
    }

    #pragma unroll
    for (int j = 0; j < 4; ++j) {
        float4* s = (float4*)(summ + ((size_t)(e0 + j) * C + c) * 8);
        s[0] = make_float4(p[j], q[j], s2[j], spq[j]);
        s[1] = make_float4(sq2[j], slpp[j], slpq[j], 0.f);
    }

    // block-reduce entropy partial (deterministic, no atomics)
    #pragma unroll
    for (int o = 32; o > 0; o >>= 1) sent += __shfl_down(sent, o, 64);
    __shared__ float ls[4];
    const int lane = threadIdx.x & 63, w = threadIdx.x >> 6;
    if (lane == 0) ls[w] = sent;
    __syncthreads();
    if (threadIdx.x == 0) entp[blockIdx.x] = (ls[0] + ls[1]) + (ls[2] + ls[3]);
}

// Pass 2 (+fused final): per-env ordered monoid tree-reduce; the last block
// to finish performs the final scalar reduction (device-scope atomics).
__global__ __launch_bounds__(256) void gae_pass2(
    const float* __restrict__ summ, const float* __restrict__ entp,
    float* __restrict__ part, unsigned int* __restrict__ cnt,
    float* __restrict__ out)
{
    const int tid  = threadIdx.x;
    const int lane = tid & 63;
    const int w    = tid >> 6;
    const int env  = blockIdx.x * 4 + w;
    const int K    = C >> 6;                // chunks per lane
    const int c_hi = C - 1 - lane * K;

    const float* base = summ + ((size_t)env * C + c_hi) * 8;
    float4 a0 = ((const float4*)base)[0];
    float4 a1 = ((const float4*)base)[1];
    Seg cur = { a0.x, a0.y, a0.z, a0.w, a1.x, a1.y, a1.z };

    #pragma unroll
    for (int j = 1; j < K; ++j) {
        const float* bp = summ + ((size_t)env * C + (c_hi - j)) * 8;
        float4 b0 = ((const float4*)bp)[0];
        float4 b1 = ((const float4*)bp)[1];
        Seg A = { b0.x, b0.y, b0.z, b0.w, b1.x, b1.y, b1.z };
        cur = seg_combine(A, cur);          // A is earlier time (outer)
    }

    #pragma unroll
    for (int d = 1; d < 64; d <<= 1) {
        Seg o;
        o.P    = __shfl_down(cur.P,    d, 64);
        o.Q    = __shfl_down(cur.Q,    d, 64);
        o.s2   = __shfl_down(cur.s2,   d, 64);
        o.spq  = __shfl_down(cur.spq,  d, 64);
        o.sq2  = __shfl_down(cur.sq2,  d, 64);
        o.slpp = __shfl_down(cur.slpp, d, 64);
        o.slpq = __shfl_down(cur.slpq, d, 64);
        cur = seg_combine(o, cur);          // higher lane = earlier = outer
    }

    if (lane == 0) {   // x = 0 at the latest timestep
        __hip_atomic_store(&part[env * 2 + 0], cur.s2,
                           __ATOMIC_RELAXED, __HIP_MEMORY_SCOPE_AGENT);
        __hip_atomic_store(&part[env * 2 + 1], cur.slpp,
                           __ATOMIC_RELAXED, __HIP_MEMORY_SCOPE_AGENT);
    }

    __shared__ unsigned int slast;
    __syncthreads();
    if (tid == 0) {
        __threadfence();                               // publish part[]
        unsigned int o = atomicAdd(cnt, 1u);           // device scope
        slast = (o == gridDim.x - 1) ? 1u : 0u;
    }
    __syncthreads();
    if (!slast) return;

    // ---- last block: final scalar reduction ----
    __threadfence();
    float crit = 0.f, act = 0.f, ent = 0.f;
    for (int i = tid; i < NENV; i += 256) {
        crit += __hip_atomic_load(&part[2 * i + 0],
                                  __ATOMIC_RELAXED, __HIP_MEMORY_SCOPE_AGENT);
        act  += __hip_atomic_load(&part[2 * i + 1],
                                  __ATOMIC_RELAXED, __HIP_MEMORY_SCOPE_AGENT);
    }
    for (int i = tid; i < C; i += 256) ent += entp[i];  // cross-dispatch: plain

    #pragma unroll
    for (int o = 32; o > 0; o >>= 1) {
        crit += __shfl_down(crit, o, 64);
        act  += __shfl_down(act,  o, 64);
        ent  += __shfl_down(ent,  o, 64);
    }
    __shared__ float lc[4], la[4], le[4];
    if (lane == 0) { lc[w] = crit; la[w] = act; le[w] = ent; }
    __syncthreads();
    if (tid == 0) {
        crit = (lc[0] + lc[1]) + (lc[2] + lc[3]);
        act  = (la[0] + la[1]) + (la[2] + la[3]);
        ent  = (le[0] + le[1]) + (le[2] + le[3]);
        const float inv = 1.f / (float)((size_t)T * NENV);
        out[0] = crit * inv;
        out[1] = -act * inv - 0.01f * (ent * inv);
    }
}

extern "C" void kernel_launch(void* const* d_in, const int* in_sizes, int n_in,
                              void* d_out, int out_size, void* d_ws, size_t ws_size,
                              hipStream_t stream) {
    const float* R  = (const float*)d_in[0];
    const float* LP = (const float*)d_in[1];
    const float* V  = (const float*)d_in[2];
    const float* LV = (const float*)d_in[3];
    const float* E  = (const float*)d_in[4];
    const float* M  = (const float*)d_in[5];
    float* out = (float*)d_out;

    float* summ = (float*)d_ws;                       // C*8*NENV floats (8 MB)
    float* entp = summ + (size_t)C * 8 * NENV;        // C floats
    float* part = entp + C;                           // 2*NENV floats
    unsigned int* cnt = (unsigned int*)(part + 2 * NENV);

    gae_pass1<<<C, 256, 0, stream>>>(R, LP, V, LV, E, M, summ, entp, cnt);
    gae_pass2<<<NENV / 4, 256, 0, stream>>>(summ, entp, part, cnt, out);
}